// Round 1
// baseline (21.742 us; speedup 1.0000x reference)
//
#include <hip/hip_runtime.h>

// RoPE transform: out[b,s,f] = Q_f @ R[b,s,f] @ Q_f^T
// Q_f = (I - S_f)(I + S_f)^{-1} = 2*(I + S_f)^{-1} - I   (Cayley, orthogonal)
//
// Shapes: skew_params [16, 6] f32, rope_matrices [4, 8192, 16, 4, 4] f32.
// Total 4x4 blocks = 4*8192*16 = 524288. One thread per block.

#define NFREQ 16
#define TOTAL_BLOCKS (4 * 8192 * 16)
#define THREADS 256

__global__ __launch_bounds__(THREADS)
void rope_transform_kernel(const float* __restrict__ skew,
                           const float* __restrict__ Rin,
                           float* __restrict__ out)
{
    // Q staged in LDS, padded stride 17: 17*f mod 32 distinct for f in [0,16)
    // -> conflict-free reads when lane's f = lane & 15.
    __shared__ float Qs[NFREQ * 17];

    const int t = threadIdx.x;
    if (t < NFREQ) {
        // Build M = I + S for frequency t. triu order: (0,1)(0,2)(0,3)(1,2)(1,3)(2,3)
        const double p0 = skew[t * 6 + 0];
        const double p1 = skew[t * 6 + 1];
        const double p2 = skew[t * 6 + 2];
        const double p3 = skew[t * 6 + 3];
        const double p4 = skew[t * 6 + 4];
        const double p5 = skew[t * 6 + 5];
        double M[4][4] = {
            { 1.0,  p0,  p1,  p2},
            {-p0,  1.0,  p3,  p4},
            {-p1,  -p3, 1.0,  p5},
            {-p2,  -p4, -p5, 1.0}};
        double Inv[4][4] = {{1,0,0,0},{0,1,0,0},{0,0,1,0},{0,0,0,1}};
        // Gauss-Jordan without pivoting: symmetric part of M is I (SPD) -> stable.
        #pragma unroll
        for (int c = 0; c < 4; ++c) {
            const double piv = 1.0 / M[c][c];
            #pragma unroll
            for (int j = 0; j < 4; ++j) { M[c][j] *= piv; Inv[c][j] *= piv; }
            #pragma unroll
            for (int r = 0; r < 4; ++r) {
                if (r == c) continue;
                const double fac = M[r][c];
                #pragma unroll
                for (int j = 0; j < 4; ++j) {
                    M[r][j]   -= fac * M[c][j];
                    Inv[r][j] -= fac * Inv[c][j];
                }
            }
        }
        // Q = 2*Minv - I
        #pragma unroll
        for (int i = 0; i < 4; ++i)
            #pragma unroll
            for (int j = 0; j < 4; ++j)
                Qs[t * 17 + i * 4 + j] =
                    (float)(2.0 * Inv[i][j] - (i == j ? 1.0 : 0.0));
    }
    __syncthreads();

    const int idx = blockIdx.x * THREADS + t;   // one 4x4 block per thread
    const int f = idx & (NFREQ - 1);

    // Q into registers (LDS broadcast/conflict-free per padding above)
    float Q[4][4];
    #pragma unroll
    for (int i = 0; i < 4; ++i)
        #pragma unroll
        for (int j = 0; j < 4; ++j)
            Q[i][j] = Qs[f * 17 + i * 4 + j];

    const float4* Rp = reinterpret_cast<const float4*>(Rin + (size_t)idx * 16);
    const float4 r0 = Rp[0], r1 = Rp[1], r2 = Rp[2], r3 = Rp[3];
    const float R[4][4] = {{r0.x, r0.y, r0.z, r0.w},
                           {r1.x, r1.y, r1.z, r1.w},
                           {r2.x, r2.y, r2.z, r2.w},
                           {r3.x, r3.y, r3.z, r3.w}};

    // T = Q * R
    float T[4][4];
    #pragma unroll
    for (int i = 0; i < 4; ++i)
        #pragma unroll
        for (int k = 0; k < 4; ++k)
            T[i][k] = Q[i][0] * R[0][k] + Q[i][1] * R[1][k]
                    + Q[i][2] * R[2][k] + Q[i][3] * R[3][k];

    // O = T * Q^T  -> O[i][k] = sum_j T[i][j] * Q[k][j]
    float4 O[4];
    #pragma unroll
    for (int i = 0; i < 4; ++i) {
        float o[4];
        #pragma unroll
        for (int k = 0; k < 4; ++k)
            o[k] = T[i][0] * Q[k][0] + T[i][1] * Q[k][1]
                 + T[i][2] * Q[k][2] + T[i][3] * Q[k][3];
        O[i] = make_float4(o[0], o[1], o[2], o[3]);
    }

    float4* Op = reinterpret_cast<float4*>(out + (size_t)idx * 16);
    Op[0] = O[0]; Op[1] = O[1]; Op[2] = O[2]; Op[3] = O[3];
}

extern "C" void kernel_launch(void* const* d_in, const int* in_sizes, int n_in,
                              void* d_out, int out_size, void* d_ws, size_t ws_size,
                              hipStream_t stream)
{
    const float* skew = (const float*)d_in[0];   // [16, 6]
    const float* Rin  = (const float*)d_in[1];   // [4, 8192, 16, 4, 4]
    float* out        = (float*)d_out;           // same shape as Rin

    rope_transform_kernel<<<TOTAL_BLOCKS / THREADS, THREADS, 0, stream>>>(
        skew, Rin, out);
}

// Round 2
// 21.177 us; speedup vs baseline: 1.0267x; 1.0267x over previous
//
#include <hip/hip_runtime.h>

// RoPE transform: out[b,s,f] = Q_f @ R[b,s,f] @ Q_f^T
// Q_f = (I - S_f)(I + S_f)^{-1} = 2*(I + S_f)^{-1} - I   (Cayley, orthogonal)
//
// Shapes: skew_params [16, 6] f32, rope_matrices [4, 8192, 16, 4, 4] f32.
//
// Two kernels:
//  1. compute_Q_kernel: 16 lanes invert (I+S)_f in f64, write Q [16][16] to ws.
//  2. rope_rows_kernel: one lane per 4x4-matrix ROW (2M rows). Lane-contiguous
//     float4 load/store (perfect coalescing); rows exchanged within each
//     aligned 4-lane quad via DPP quad_perm broadcasts; Q read from LDS.

#define NFREQ 16
#define NROWS (4 * 8192 * 16 * 4)   // 2,097,152 rows
#define THREADS 256
#define QPAD 20                      // row stride in floats: 80B, 16B-aligned

__global__ void compute_Q_kernel(const float* __restrict__ skew,
                                 float* __restrict__ Qg)
{
    const int t = threadIdx.x;
    if (t >= NFREQ) return;
    // M = I + S. triu order: (0,1)(0,2)(0,3)(1,2)(1,3)(2,3)
    const double p0 = skew[t * 6 + 0];
    const double p1 = skew[t * 6 + 1];
    const double p2 = skew[t * 6 + 2];
    const double p3 = skew[t * 6 + 3];
    const double p4 = skew[t * 6 + 4];
    const double p5 = skew[t * 6 + 5];
    double M[4][4] = {
        { 1.0,  p0,  p1,  p2},
        {-p0,  1.0,  p3,  p4},
        {-p1,  -p3, 1.0,  p5},
        {-p2,  -p4, -p5, 1.0}};
    double Inv[4][4] = {{1,0,0,0},{0,1,0,0},{0,0,1,0},{0,0,0,1}};
    // Gauss-Jordan, no pivoting (symmetric part of M is I -> SPD-stable).
    #pragma unroll
    for (int c = 0; c < 4; ++c) {
        const double piv = 1.0 / M[c][c];
        #pragma unroll
        for (int j = 0; j < 4; ++j) { M[c][j] *= piv; Inv[c][j] *= piv; }
        #pragma unroll
        for (int r = 0; r < 4; ++r) {
            if (r == c) continue;
            const double fac = M[r][c];
            #pragma unroll
            for (int j = 0; j < 4; ++j) {
                M[r][j]   -= fac * M[c][j];
                Inv[r][j] -= fac * Inv[c][j];
            }
        }
    }
    #pragma unroll
    for (int i = 0; i < 4; ++i)
        #pragma unroll
        for (int j = 0; j < 4; ++j)
            Qg[t * 16 + i * 4 + j] =
                (float)(2.0 * Inv[i][j] - (i == j ? 1.0 : 0.0));
}

// Broadcast lane (quadbase + J)'s value to all 4 lanes of the quad. Free VALU.
template <int J>
__device__ __forceinline__ float4 quad_bcast(float4 v)
{
    constexpr int ctrl = J * 0x55;   // J | J<<2 | J<<4 | J<<6
    float4 o;
    o.x = __int_as_float(__builtin_amdgcn_mov_dpp(__float_as_int(v.x), ctrl, 0xF, 0xF, true));
    o.y = __int_as_float(__builtin_amdgcn_mov_dpp(__float_as_int(v.y), ctrl, 0xF, 0xF, true));
    o.z = __int_as_float(__builtin_amdgcn_mov_dpp(__float_as_int(v.z), ctrl, 0xF, 0xF, true));
    o.w = __int_as_float(__builtin_amdgcn_mov_dpp(__float_as_int(v.w), ctrl, 0xF, 0xF, true));
    return o;
}

__device__ __forceinline__ float dot4(float4 a, float4 b)
{
    return a.x * b.x + a.y * b.y + a.z * b.z + a.w * b.w;
}

__global__ __launch_bounds__(THREADS)
void rope_rows_kernel(const float* __restrict__ Qg,
                      const float* __restrict__ Rin,
                      float* __restrict__ out)
{
    __shared__ float Qs[NFREQ * QPAD];

    const int t = threadIdx.x;
    // Coalesced 1KB Q load: thread t -> freq t>>4, elem t&15.
    Qs[(t >> 4) * QPAD + (t & 15)] = Qg[t];
    __syncthreads();

    const int g = blockIdx.x * THREADS + t;   // global row id
    const int i = g & 3;                      // row within 4x4 block
    const int f = (g >> 2) & (NFREQ - 1);     // frequency

    // Perfectly coalesced: lane-contiguous 16B.
    const float4 r = reinterpret_cast<const float4*>(Rin)[g];

    const float4* Qrow = reinterpret_cast<const float4*>(&Qs[f * QPAD]);
    const float4 q0 = Qrow[0], q1 = Qrow[1], q2 = Qrow[2], q3 = Qrow[3];
    const float4 qi = Qrow[i];                // own row of Q

    // T row i = sum_j Q[i][j] * (R row j); R rows live in the quad's lanes.
    float4 T;
    {
        const float4 r0 = quad_bcast<0>(r);
        T.x = qi.x * r0.x; T.y = qi.x * r0.y; T.z = qi.x * r0.z; T.w = qi.x * r0.w;
        const float4 r1 = quad_bcast<1>(r);
        T.x += qi.y * r1.x; T.y += qi.y * r1.y; T.z += qi.y * r1.z; T.w += qi.y * r1.w;
        const float4 r2 = quad_bcast<2>(r);
        T.x += qi.z * r2.x; T.y += qi.z * r2.y; T.z += qi.z * r2.z; T.w += qi.z * r2.w;
        const float4 r3 = quad_bcast<3>(r);
        T.x += qi.w * r3.x; T.y += qi.w * r3.y; T.z += qi.w * r3.z; T.w += qi.w * r3.w;
    }

    // O row i = T . Q^T rows  ->  O[i][k] = dot(T, Q row k)
    float4 o;
    o.x = dot4(T, q0);
    o.y = dot4(T, q1);
    o.z = dot4(T, q2);
    o.w = dot4(T, q3);

    reinterpret_cast<float4*>(out)[g] = o;    // coalesced 16B/lane
}

extern "C" void kernel_launch(void* const* d_in, const int* in_sizes, int n_in,
                              void* d_out, int out_size, void* d_ws, size_t ws_size,
                              hipStream_t stream)
{
    const float* skew = (const float*)d_in[0];   // [16, 6]
    const float* Rin  = (const float*)d_in[1];   // [4, 8192, 16, 4, 4]
    float* out        = (float*)d_out;
    float* Qg         = (float*)d_ws;            // [16][16] floats = 1KB

    compute_Q_kernel<<<1, 64, 0, stream>>>(skew, Qg);
    rope_rows_kernel<<<NROWS / THREADS, THREADS, 0, stream>>>(Qg, Rin, out);
}